// Round 5
// baseline (1076.284 us; speedup 1.0000x reference)
//
#include <hip/hip_runtime.h>
#include <hip/hip_bf16.h>
#include <stdint.h>

typedef __attribute__((ext_vector_type(8))) __bf16 bf16x8;
typedef __attribute__((ext_vector_type(4))) float f32x4;

#define BM 128
#define BN 128
#define BK 64

// 256x256x32 pipelined GEMM geometry
#define GBM 256
#define GBN 256
#define GBK 32

__device__ inline void gload_lds16(const void* g, void* l) {
    __builtin_amdgcn_global_load_lds(
        (const __attribute__((address_space(1))) uint32_t*)g,
        (__attribute__((address_space(3))) uint32_t*)l, 16, 0, 0);
}

// ---------------- pass 1a: X f32 -> bf16 ----------------
__global__ __launch_bounds__(256)
void cvt_x(const float* __restrict__ X, __bf16* __restrict__ Xb, size_t n8) {
    for (size_t i = blockIdx.x * 256ull + threadIdx.x; i < n8; i += (size_t)gridDim.x * 256ull) {
        const float4 x0 = *(const float4*)(X + i * 8);
        const float4 x1 = *(const float4*)(X + i * 8 + 4);
        bf16x8 v;
        v[0] = (__bf16)x0.x; v[1] = (__bf16)x0.y; v[2] = (__bf16)x0.z; v[3] = (__bf16)x0.w;
        v[4] = (__bf16)x1.x; v[5] = (__bf16)x1.y; v[6] = (__bf16)x1.z; v[7] = (__bf16)x1.w;
        *((bf16x8*)(Xb + i * 8)) = v;
    }
}

// ---------------- pass 1b: dequant W -> bf16 [N][K] ----------------
__global__ __launch_bounds__(128)
void dequant_w(const int* __restrict__ QW, const int* __restrict__ QZ,
               const float* __restrict__ S, __bf16* __restrict__ W, int N, int K) {
    const int PQ = K >> 3, NG = K >> 7, ZS = (NG + 7) >> 3;
    const int o = blockIdx.x;
    const int c = threadIdx.x;            // 0..K/32-1
    const int k0 = c * 32;
    const int g = k0 >> 7;
    const int zq = (QZ[(size_t)o * ZS + (g >> 3)] >> ((g & 7) * 4)) & 15;
    const float sf = S[(size_t)o * NG + g];
    const float zs = (float)zq * sf;
    const int4 qv = *(const int4*)(QW + (size_t)o * PQ + c * 4);
    const int vs[4] = {qv.x, qv.y, qv.z, qv.w};
#pragma unroll
    for (int w = 0; w < 4; ++w) {
        const int v = vs[w];
        bf16x8 wv;
#pragma unroll
        for (int j = 0; j < 8; ++j) {
            const float q = (float)((v >> (4 * j)) & 15);
            wv[j] = (__bf16)(q * sf - zs);
        }
        *((bf16x8*)(W + (size_t)o * K + k0 + w * 8)) = wv;
    }
}

// ---------------- pass 2: 256x256 pipelined bf16 GEMM ----------------
// 512 threads = 8 waves (2 wm x 4 wn); per-wave output 128x64 (acc[8][4]).
// LDS: 2 bufs x (A[256][32] + B[256][32]) bf16 = 64 KB. 64B rows -> every
// ds_read_b128 fragment covers a contiguous 1KB -> bank-conflict-free.
// Pipeline: stage tile t+1 (4 x gload_lds) issued inside tile t's phase 1;
// waited at tile t+1's phase-1 vmcnt(0)+barrier (queue holds only those 4).
__global__ __launch_bounds__(512, 2)
void gemm_8p(const __bf16* __restrict__ A, const __bf16* __restrict__ B,
             const float* __restrict__ Bi, float* __restrict__ Out,
             int M, int N, int K) {
    __shared__ __align__(16) __bf16 sA[2][GBM * GBK];  // 2 x 16 KB
    __shared__ __align__(16) __bf16 sB[2][GBN * GBK];  // 2 x 16 KB

    const int tid  = threadIdx.x;
    const int lane = tid & 63;
    const int wid  = tid >> 6;
    const int wm   = wid >> 2;   // 0..1
    const int wn   = wid & 3;    // 0..3

    // XCD-chunked swizzle over col-major tile order (nwg = 1376 = 8*172)
    int bid = blockIdx.x;
    {
        const int nwg = gridDim.x;
        if ((nwg & 7) == 0) {
            const int cpx = nwg >> 3;
            bid = (bid & 7) * cpx + (bid >> 3);
        }
    }
    const int nbm  = M / GBM;               // 32
    const int brow = (bid % nbm) * GBM;     // col-major: B-panel L2-resident
    const int bcol = (bid / nbm) * GBN;

    // staging geometry: 1024 16B-slots per tile per matrix; 2 per thread
    const int s0 = tid, s1 = tid + 512;
    const int ra0 = s0 >> 2, ca0 = s0 & 3;
    const int ra1 = s1 >> 2, ca1 = s1 & 3;
    const __bf16* pA0 = A + (size_t)(brow + ra0) * K + ca0 * 8;
    const __bf16* pA1 = A + (size_t)(brow + ra1) * K + ca1 * 8;
    const __bf16* pB0 = B + (size_t)(bcol + ra0) * K + ca0 * 8;
    const __bf16* pB1 = B + (size_t)(bcol + ra1) * K + ca1 * 8;
    // wave-uniform LDS byte bases (HW adds lane*16)
    const int lb0 = wid * 1024;
    const int lb1 = wid * 1024 + 8192;

    f32x4 acc[8][4];
#pragma unroll
    for (int i = 0; i < 8; ++i)
#pragma unroll
        for (int j = 0; j < 4; ++j)
            acc[i][j] = {0.f, 0.f, 0.f, 0.f};

    const int NT = K / GBK;   // 128

#define STAGE(BUF, KT)                                                          \
    do {                                                                        \
        gload_lds16(pA0 + (KT) * GBK, (char*)(&sA[(BUF)][0]) + lb0);            \
        gload_lds16(pA1 + (KT) * GBK, (char*)(&sA[(BUF)][0]) + lb1);            \
        gload_lds16(pB0 + (KT) * GBK, (char*)(&sB[(BUF)][0]) + lb0);            \
        gload_lds16(pB1 + (KT) * GBK, (char*)(&sB[(BUF)][0]) + lb1);            \
    } while (0)

#define LOADA(BUF, MI) \
    (*((const bf16x8*)(&sA[(BUF)][0] + ((wm * 128 + (MI) * 16 + (lane & 15)) * GBK + (lane >> 4) * 8))))
#define LOADB(BUF, NI) \
    (*((const bf16x8*)(&sB[(BUF)][0] + ((wn * 64 + (NI) * 16 + (lane & 15)) * GBK + (lane >> 4) * 8))))

#define HALF_ITER(B_, T_)                                                       \
    do {                                                                        \
        /* P1: wait own stage loads, cross-wave barrier, then read */           \
        asm volatile("s_waitcnt vmcnt(0)" ::: "memory");                        \
        __builtin_amdgcn_sched_barrier(0);                                      \
        __builtin_amdgcn_s_barrier();                                           \
        __builtin_amdgcn_sched_barrier(0);                                      \
        bf16x8 af0 = LOADA(B_, 0), af1 = LOADA(B_, 1);                          \
        bf16x8 af2 = LOADA(B_, 2), af3 = LOADA(B_, 3);                          \
        bf16x8 bf0 = LOADB(B_, 0), bf1 = LOADB(B_, 1);                          \
        bf16x8 bf2 = LOADB(B_, 2), bf3 = LOADB(B_, 3);                          \
        if ((T_) + 1 < NT) STAGE(1 - (B_), (T_) + 1);                           \
        __builtin_amdgcn_sched_barrier(0);                                      \
        __builtin_amdgcn_s_setprio(1);                                          \
        acc[0][0] = __builtin_amdgcn_mfma_f32_16x16x32_bf16(af0, bf0, acc[0][0], 0, 0, 0); \
        acc[0][1] = __builtin_amdgcn_mfma_f32_16x16x32_bf16(af0, bf1, acc[0][1], 0, 0, 0); \
        acc[0][2] = __builtin_amdgcn_mfma_f32_16x16x32_bf16(af0, bf2, acc[0][2], 0, 0, 0); \
        acc[0][3] = __builtin_amdgcn_mfma_f32_16x16x32_bf16(af0, bf3, acc[0][3], 0, 0, 0); \
        acc[1][0] = __builtin_amdgcn_mfma_f32_16x16x32_bf16(af1, bf0, acc[1][0], 0, 0, 0); \
        acc[1][1] = __builtin_amdgcn_mfma_f32_16x16x32_bf16(af1, bf1, acc[1][1], 0, 0, 0); \
        acc[1][2] = __builtin_amdgcn_mfma_f32_16x16x32_bf16(af1, bf2, acc[1][2], 0, 0, 0); \
        acc[1][3] = __builtin_amdgcn_mfma_f32_16x16x32_bf16(af1, bf3, acc[1][3], 0, 0, 0); \
        acc[2][0] = __builtin_amdgcn_mfma_f32_16x16x32_bf16(af2, bf0, acc[2][0], 0, 0, 0); \
        acc[2][1] = __builtin_amdgcn_mfma_f32_16x16x32_bf16(af2, bf1, acc[2][1], 0, 0, 0); \
        acc[2][2] = __builtin_amdgcn_mfma_f32_16x16x32_bf16(af2, bf2, acc[2][2], 0, 0, 0); \
        acc[2][3] = __builtin_amdgcn_mfma_f32_16x16x32_bf16(af2, bf3, acc[2][3], 0, 0, 0); \
        acc[3][0] = __builtin_amdgcn_mfma_f32_16x16x32_bf16(af3, bf0, acc[3][0], 0, 0, 0); \
        acc[3][1] = __builtin_amdgcn_mfma_f32_16x16x32_bf16(af3, bf1, acc[3][1], 0, 0, 0); \
        acc[3][2] = __builtin_amdgcn_mfma_f32_16x16x32_bf16(af3, bf2, acc[3][2], 0, 0, 0); \
        acc[3][3] = __builtin_amdgcn_mfma_f32_16x16x32_bf16(af3, bf3, acc[3][3], 0, 0, 0); \
        __builtin_amdgcn_s_setprio(0);                                          \
        __builtin_amdgcn_sched_barrier(0);                                      \
        /* P2: remaining m-half, reuse B frags */                               \
        bf16x8 ag0 = LOADA(B_, 4), ag1 = LOADA(B_, 5);                          \
        bf16x8 ag2 = LOADA(B_, 6), ag3 = LOADA(B_, 7);                          \
        __builtin_amdgcn_s_setprio(1);                                          \
        acc[4][0] = __builtin_amdgcn_mfma_f32_16x16x32_bf16(ag0, bf0, acc[4][0], 0, 0, 0); \
        acc[4][1] = __builtin_amdgcn_mfma_f32_16x16x32_bf16(ag0, bf1, acc[4][1], 0, 0, 0); \
        acc[4][2] = __builtin_amdgcn_mfma_f32_16x16x32_bf16(ag0, bf2, acc[4][2], 0, 0, 0); \
        acc[4][3] = __builtin_amdgcn_mfma_f32_16x16x32_bf16(ag0, bf3, acc[4][3], 0, 0, 0); \
        acc[5][0] = __builtin_amdgcn_mfma_f32_16x16x32_bf16(ag1, bf0, acc[5][0], 0, 0, 0); \
        acc[5][1] = __builtin_amdgcn_mfma_f32_16x16x32_bf16(ag1, bf1, acc[5][1], 0, 0, 0); \
        acc[5][2] = __builtin_amdgcn_mfma_f32_16x16x32_bf16(ag1, bf2, acc[5][2], 0, 0, 0); \
        acc[5][3] = __builtin_amdgcn_mfma_f32_16x16x32_bf16(ag1, bf3, acc[5][3], 0, 0, 0); \
        acc[6][0] = __builtin_amdgcn_mfma_f32_16x16x32_bf16(ag2, bf0, acc[6][0], 0, 0, 0); \
        acc[6][1] = __builtin_amdgcn_mfma_f32_16x16x32_bf16(ag2, bf1, acc[6][1], 0, 0, 0); \
        acc[6][2] = __builtin_amdgcn_mfma_f32_16x16x32_bf16(ag2, bf2, acc[6][2], 0, 0, 0); \
        acc[6][3] = __builtin_amdgcn_mfma_f32_16x16x32_bf16(ag2, bf3, acc[6][3], 0, 0, 0); \
        acc[7][0] = __builtin_amdgcn_mfma_f32_16x16x32_bf16(ag3, bf0, acc[7][0], 0, 0, 0); \
        acc[7][1] = __builtin_amdgcn_mfma_f32_16x16x32_bf16(ag3, bf1, acc[7][1], 0, 0, 0); \
        acc[7][2] = __builtin_amdgcn_mfma_f32_16x16x32_bf16(ag3, bf2, acc[7][2], 0, 0, 0); \
        acc[7][3] = __builtin_amdgcn_mfma_f32_16x16x32_bf16(ag3, bf3, acc[7][3], 0, 0, 0); \
        __builtin_amdgcn_s_setprio(0);                                          \
        __builtin_amdgcn_sched_barrier(0);                                      \
    } while (0)

    STAGE(0, 0);   // prologue: tile 0 -> buf0

    for (int tp = 0; tp < NT; tp += 2) {
        HALF_ITER(0, tp);
        HALF_ITER(1, tp + 1);
    }

#undef HALF_ITER
#undef LOADB
#undef LOADA
#undef STAGE

    // epilogue: frag layout col=lane&15, row=(lane>>4)*4+r
    const int cr0 = brow + wm * 128;
    const int cc0 = bcol + wn * 64;
#pragma unroll
    for (int ni = 0; ni < 4; ++ni) {
        const int col = cc0 + ni * 16 + (lane & 15);
        const float bv = Bi[col];
#pragma unroll
        for (int mi = 0; mi < 8; ++mi) {
#pragma unroll
            for (int r = 0; r < 4; ++r) {
                const int row = cr0 + mi * 16 + (lane >> 4) * 4 + r;
                Out[(size_t)row * N + col] = acc[mi][ni][r] + bv;
            }
        }
    }
}

// ---------------- fallback: fused kernel (ws too small) ----------------
__global__ __launch_bounds__(256, 3)
void awq_gemm_fused(const float* __restrict__ X,
                    const int* __restrict__ QW,
                    const int* __restrict__ QZ,
                    const float* __restrict__ S,
                    const float* __restrict__ Bi,
                    float* __restrict__ Out,
                    int M, int N, int K) {
    const int PQ = K >> 3, NG = K >> 7, ZS = (NG + 7) >> 3;

    __shared__ __align__(16) __bf16 As[BM * BK];
    __shared__ __align__(16) __bf16 Bs[BN * BK];

    const int tid  = threadIdx.x;
    const int lane = tid & 63;
    const int wid  = tid >> 6;

    const int nwg = gridDim.x;
    int bid = blockIdx.x;
    if ((nwg & 7) == 0) {
        const int cpx = nwg >> 3;
        bid = (bid & 7) * cpx + (bid >> 3);
    }
    const int nbn  = N / BN;
    const int brow = (bid / nbn) * BM;
    const int bcol = (bid % nbn) * BN;

    const int wm = wid >> 1;
    const int wn = wid & 1;

    f32x4 acc[4][4];
#pragma unroll
    for (int i = 0; i < 4; ++i)
#pragma unroll
        for (int j = 0; j < 4; ++j)
            acc[i][j] = {0.f, 0.f, 0.f, 0.f};

    int arow[4], acch[4];
#pragma unroll
    for (int it = 0; it < 4; ++it) {
        const int idx = it * 256 + tid;
        arow[it] = idx >> 3;
        acch[it] = idx & 7;
    }

    const int rb    = tid >> 1;
    const int bhalf = tid & 1;
    const int og    = bcol + rb;
    const int* qwrow = QW + (size_t)og * PQ;
    const int* qzrow = QZ + (size_t)og * ZS;
    const float* srow = S + (size_t)og * NG;

    for (int kk = 0; kk < K; kk += BK) {
        bf16x8 areg[4];
#pragma unroll
        for (int it = 0; it < 4; ++it) {
            const float* gx = X + (size_t)(brow + arow[it]) * K + kk + acch[it] * 8;
            const float4 x0 = *(const float4*)gx;
            const float4 x1 = *(const float4*)(gx + 4);
            areg[it][0] = (__bf16)x0.x; areg[it][1] = (__bf16)x0.y;
            areg[it][2] = (__bf16)x0.z; areg[it][3] = (__bf16)x0.w;
            areg[it][4] = (__bf16)x1.x; areg[it][5] = (__bf16)x1.y;
            areg[it][6] = (__bf16)x1.z; areg[it][7] = (__bf16)x1.w;
        }

        const int4 qv = *(const int4*)(qwrow + (kk >> 3) + bhalf * 4);
        const int g  = kk >> 7;
        const int zq = (qzrow[g >> 3] >> ((g & 7) * 4)) & 15;
        const float sf = srow[g];
        const float zs = (float)zq * sf;
        const int vs[4] = {qv.x, qv.y, qv.z, qv.w};
        bf16x8 wregs[4];
#pragma unroll
        for (int w = 0; w < 4; ++w) {
            const int v = vs[w];
#pragma unroll
            for (int j = 0; j < 8; ++j) {
                const float q = (float)((v >> (4 * j)) & 15);
                wregs[w][j] = (__bf16)(q * sf - zs);
            }
        }

#pragma unroll
        for (int it = 0; it < 4; ++it) {
            const int cs = acch[it] ^ (arow[it] & 7);
            *((bf16x8*)(As + (size_t)arow[it] * BK + cs * 8)) = areg[it];
        }
#pragma unroll
        for (int w = 0; w < 4; ++w) {
            const int cs = (bhalf * 4 + w) ^ (rb & 7);
            *((bf16x8*)(Bs + (size_t)rb * BK + cs * 8)) = wregs[w];
        }

        __syncthreads();

#pragma unroll
        for (int ks = 0; ks < 2; ++ks) {
            bf16x8 af[4], bfr[4];
#pragma unroll
            for (int mi = 0; mi < 4; ++mi) {
                const int row = wm * 64 + mi * 16 + (lane & 15);
                const int cs  = (ks * 4 + (lane >> 4)) ^ (row & 7);
                af[mi] = *((const bf16x8*)(As + (size_t)row * BK + cs * 8));
            }
#pragma unroll
            for (int ni = 0; ni < 4; ++ni) {
                const int row = wn * 64 + ni * 16 + (lane & 15);
                const int cs  = (ks * 4 + (lane >> 4)) ^ (row & 7);
                bfr[ni] = *((const bf16x8*)(Bs + (size_t)row * BK + cs * 8));
            }
#pragma unroll
            for (int mi = 0; mi < 4; ++mi)
#pragma unroll
                for (int ni = 0; ni < 4; ++ni)
                    acc[mi][ni] = __builtin_amdgcn_mfma_f32_16x16x32_bf16(
                        af[mi], bfr[ni], acc[mi][ni], 0, 0, 0);
        }
        __syncthreads();
    }

    const int cr0 = brow + wm * 64;
    const int cc0 = bcol + wn * 64;
#pragma unroll
    for (int ni = 0; ni < 4; ++ni) {
        const int col = cc0 + ni * 16 + (lane & 15);
        const float bv = Bi[col];
#pragma unroll
        for (int mi = 0; mi < 4; ++mi) {
#pragma unroll
            for (int r = 0; r < 4; ++r) {
                const int row = cr0 + mi * 16 + (lane >> 4) * 4 + r;
                Out[(size_t)row * N + col] = acc[mi][ni][r] + bv;
            }
        }
    }
}

extern "C" void kernel_launch(void* const* d_in, const int* in_sizes, int n_in,
                              void* d_out, int out_size, void* d_ws, size_t ws_size,
                              hipStream_t stream) {
    const float* X  = (const float*)d_in[0];
    const int*   QW = (const int*)d_in[1];
    const int*   QZ = (const int*)d_in[2];
    const float* S  = (const float*)d_in[3];
    const float* Bi = (const float*)d_in[4];
    float*       Out = (float*)d_out;

    const int O = in_sizes[4];           // 11008
    const int K = in_sizes[1] / O * 8;   // 4096
    const int M = in_sizes[0] / K;       // 8192

    const size_t szX = (size_t)M * K * sizeof(__bf16);   // 64 MiB
    const size_t szW = (size_t)O * K * sizeof(__bf16);   // 86 MiB

    if (ws_size >= szX + szW) {
        __bf16* Xb = (__bf16*)d_ws;
        __bf16* Wb = (__bf16*)((char*)d_ws + szX);
        const size_t n8 = (size_t)M * K / 8;
        cvt_x<<<2048, 256, 0, stream>>>(X, Xb, n8);
        dequant_w<<<O, K / 32, 0, stream>>>(QW, QZ, S, Wb, O, K);
        const int grid = (M / GBM) * (O / GBN);   // 32*43 = 1376
        gemm_8p<<<grid, 512, 0, stream>>>(Xb, Wb, Bi, Out, M, O, K);
    } else {
        const int grid = (M / BM) * (O / BN);
        awq_gemm_fused<<<grid, 256, 0, stream>>>(X, QW, QZ, S, Bi, Out, M, O, K);
    }
}

// Round 6
// 954.256 us; speedup vs baseline: 1.1279x; 1.1279x over previous
//
#include <hip/hip_runtime.h>
#include <hip/hip_bf16.h>
#include <stdint.h>

typedef __attribute__((ext_vector_type(8))) __bf16 bf16x8;
typedef __attribute__((ext_vector_type(4))) float f32x4;

#define BM 128
#define BN 128
#define BK 64

// pipelined GEMM geometry: 256x256 tile, K-step 32, 4-deep LDS ring
#define GBM 256
#define GBN 256
#define GBK 32
#define NBUF 4

__device__ inline void gload_lds16(const void* g, void* l) {
    __builtin_amdgcn_global_load_lds(
        (const __attribute__((address_space(1))) uint32_t*)g,
        (__attribute__((address_space(3))) uint32_t*)l, 16, 0, 0);
}

// ---------------- pass 1a: X f32 -> bf16 ----------------
__global__ __launch_bounds__(256)
void cvt_x(const float* __restrict__ X, __bf16* __restrict__ Xb, size_t n8) {
    for (size_t i = blockIdx.x * 256ull + threadIdx.x; i < n8; i += (size_t)gridDim.x * 256ull) {
        const float4 x0 = *(const float4*)(X + i * 8);
        const float4 x1 = *(const float4*)(X + i * 8 + 4);
        bf16x8 v;
        v[0] = (__bf16)x0.x; v[1] = (__bf16)x0.y; v[2] = (__bf16)x0.z; v[3] = (__bf16)x0.w;
        v[4] = (__bf16)x1.x; v[5] = (__bf16)x1.y; v[6] = (__bf16)x1.z; v[7] = (__bf16)x1.w;
        *((bf16x8*)(Xb + i * 8)) = v;
    }
}

// ---------------- pass 1b: dequant W -> bf16 [N][K] ----------------
__global__ __launch_bounds__(128)
void dequant_w(const int* __restrict__ QW, const int* __restrict__ QZ,
               const float* __restrict__ S, __bf16* __restrict__ W, int N, int K) {
    const int PQ = K >> 3, NG = K >> 7, ZS = (NG + 7) >> 3;
    const int o = blockIdx.x;
    const int c = threadIdx.x;            // 0..K/32-1
    const int k0 = c * 32;
    const int g = k0 >> 7;
    const int zq = (QZ[(size_t)o * ZS + (g >> 3)] >> ((g & 7) * 4)) & 15;
    const float sf = S[(size_t)o * NG + g];
    const float zs = (float)zq * sf;
    const int4 qv = *(const int4*)(QW + (size_t)o * PQ + c * 4);
    const int vs[4] = {qv.x, qv.y, qv.z, qv.w};
#pragma unroll
    for (int w = 0; w < 4; ++w) {
        const int v = vs[w];
        bf16x8 wv;
#pragma unroll
        for (int j = 0; j < 8; ++j) {
            const float q = (float)((v >> (4 * j)) & 15);
            wv[j] = (__bf16)(q * sf - zs);
        }
        *((bf16x8*)(W + (size_t)o * K + k0 + w * 8)) = wv;
    }
}

// ---------------- pass 2: deep-pipelined 256x256 bf16 GEMM ----------------
// 512 threads = 8 waves (2 wm x 4 wn); per-wave output 128x64 (acc[8][4]).
// LDS ring: 4 bufs x (A[256][32] + B[256][32]) bf16 = 128 KB -> 1 block/CU.
// Depth-3 prefetch with counted vmcnt(8) (T4): stage tile t+3 inside tile t;
// steady-state queue holds 3 tiles x 4 loads; vmcnt(8) at top of tile t
// retires exactly tile t's loads. Per-wave wait + s_barrier => all waves'
// tile-t loads visible. Drain to 0 only in the 3-tile tail.
// LDS chunk-XOR (c ^= (row>>1)&3) via pre-swizzled GLOBAL source (linear
// gload_lds dest) + swizzled read offset -> uniform bank use (no conflicts).
__global__ __launch_bounds__(512, 2)
void gemm_pipe(const __bf16* __restrict__ A, const __bf16* __restrict__ B,
               const float* __restrict__ Bi, float* __restrict__ Out,
               int M, int N, int K) {
    __shared__ __align__(16) __bf16 sA[NBUF][GBM * GBK];  // 4 x 16 KB
    __shared__ __align__(16) __bf16 sB[NBUF][GBN * GBK];  // 4 x 16 KB

    const int tid  = threadIdx.x;
    const int lane = tid & 63;
    const int wid  = tid >> 6;
    const int wm   = wid >> 2;   // 0..1
    const int wn   = wid & 3;    // 0..3

    // XCD-chunked swizzle over col-major tile order (nwg = 1376 = 8*172)
    int bid = blockIdx.x;
    {
        const int nwg = gridDim.x;
        if ((nwg & 7) == 0) {
            const int cpx = nwg >> 3;
            bid = (bid & 7) * cpx + (bid >> 3);
        }
    }
    const int nbm  = M / GBM;
    const int brow = (bid % nbm) * GBM;     // col-major: B-panel L2-resident
    const int bcol = (bid / nbm) * GBN;

    // staging: 1024 16B-slots per matrix per tile; slot s=(row=s>>2, c_lds=s&3).
    // LDS holds global chunk c_g = c_lds ^ ((row>>1)&3)  (pre-swizzled source).
    const int s0 = tid, s1 = tid + 512;
    const int ra0 = s0 >> 2, ra1 = s1 >> 2;
    const int ca0 = (s0 & 3) ^ ((s0 >> 3) & 3);
    const int ca1 = (s1 & 3) ^ ((s1 >> 3) & 3);
    const __bf16* pA0 = A + (size_t)(brow + ra0) * K + ca0 * 8;
    const __bf16* pA1 = A + (size_t)(brow + ra1) * K + ca1 * 8;
    const __bf16* pB0 = B + (size_t)(bcol + ra0) * K + ca0 * 8;
    const __bf16* pB1 = B + (size_t)(bcol + ra1) * K + ca1 * 8;
    // wave-uniform LDS byte bases (HW adds lane*16)
    const int lb0 = wid * 1024;
    const int lb1 = wid * 1024 + 8192;

    // fragment-read swizzle: row byte = row*64 + ((q ^ ((row>>1)&3))*16)
    const int rA = lane & 15;
    const int chunkoff = ((lane >> 4) ^ ((rA >> 1) & 3)) * 16;

    f32x4 acc[8][4];
#pragma unroll
    for (int i = 0; i < 8; ++i)
#pragma unroll
        for (int j = 0; j < 4; ++j)
            acc[i][j] = {0.f, 0.f, 0.f, 0.f};

    const int NT = K / GBK;   // 128 (host guarantees NT % 4 == 0, NT >= 8)

#define STAGE(BUF_, KT_)                                                        \
    do {                                                                        \
        gload_lds16(pA0 + (size_t)(KT_) * GBK, (char*)(&sA[(BUF_)][0]) + lb0);  \
        gload_lds16(pA1 + (size_t)(KT_) * GBK, (char*)(&sA[(BUF_)][0]) + lb1);  \
        gload_lds16(pB0 + (size_t)(KT_) * GBK, (char*)(&sB[(BUF_)][0]) + lb0);  \
        gload_lds16(pB1 + (size_t)(KT_) * GBK, (char*)(&sB[(BUF_)][0]) + lb1);  \
    } while (0)

#define LOADA(BUF_, MI) \
    (*((const bf16x8*)((const char*)(&sA[(BUF_)][0]) + (wm * 128 + (MI) * 16 + rA) * 64 + chunkoff)))
#define LOADB(BUF_, NI) \
    (*((const bf16x8*)((const char*)(&sB[(BUF_)][0]) + (wn * 64 + (NI) * 16 + rA) * 64 + chunkoff)))

#define MFMA16(A0_, A1_, A2_, A3_, ROWB_)                                                       \
    do {                                                                                        \
        acc[ROWB_ + 0][0] = __builtin_amdgcn_mfma_f32_16x16x32_bf16(A0_, bf0, acc[ROWB_ + 0][0], 0, 0, 0); \
        acc[ROWB_ + 0][1] = __builtin_amdgcn_mfma_f32_16x16x32_bf16(A0_, bf1, acc[ROWB_ + 0][1], 0, 0, 0); \
        acc[ROWB_ + 0][2] = __builtin_amdgcn_mfma_f32_16x16x32_bf16(A0_, bf2, acc[ROWB_ + 0][2], 0, 0, 0); \
        acc[ROWB_ + 0][3] = __builtin_amdgcn_mfma_f32_16x16x32_bf16(A0_, bf3, acc[ROWB_ + 0][3], 0, 0, 0); \
        acc[ROWB_ + 1][0] = __builtin_amdgcn_mfma_f32_16x16x32_bf16(A1_, bf0, acc[ROWB_ + 1][0], 0, 0, 0); \
        acc[ROWB_ + 1][1] = __builtin_amdgcn_mfma_f32_16x16x32_bf16(A1_, bf1, acc[ROWB_ + 1][1], 0, 0, 0); \
        acc[ROWB_ + 1][2] = __builtin_amdgcn_mfma_f32_16x16x32_bf16(A1_, bf2, acc[ROWB_ + 1][2], 0, 0, 0); \
        acc[ROWB_ + 1][3] = __builtin_amdgcn_mfma_f32_16x16x32_bf16(A1_, bf3, acc[ROWB_ + 1][3], 0, 0, 0); \
        acc[ROWB_ + 2][0] = __builtin_amdgcn_mfma_f32_16x16x32_bf16(A2_, bf0, acc[ROWB_ + 2][0], 0, 0, 0); \
        acc[ROWB_ + 2][1] = __builtin_amdgcn_mfma_f32_16x16x32_bf16(A2_, bf1, acc[ROWB_ + 2][1], 0, 0, 0); \
        acc[ROWB_ + 2][2] = __builtin_amdgcn_mfma_f32_16x16x32_bf16(A2_, bf2, acc[ROWB_ + 2][2], 0, 0, 0); \
        acc[ROWB_ + 2][3] = __builtin_amdgcn_mfma_f32_16x16x32_bf16(A2_, bf3, acc[ROWB_ + 2][3], 0, 0, 0); \
        acc[ROWB_ + 3][0] = __builtin_amdgcn_mfma_f32_16x16x32_bf16(A3_, bf0, acc[ROWB_ + 3][0], 0, 0, 0); \
        acc[ROWB_ + 3][1] = __builtin_amdgcn_mfma_f32_16x16x32_bf16(A3_, bf1, acc[ROWB_ + 3][1], 0, 0, 0); \
        acc[ROWB_ + 3][2] = __builtin_amdgcn_mfma_f32_16x16x32_bf16(A3_, bf2, acc[ROWB_ + 3][2], 0, 0, 0); \
        acc[ROWB_ + 3][3] = __builtin_amdgcn_mfma_f32_16x16x32_bf16(A3_, bf3, acc[ROWB_ + 3][3], 0, 0, 0); \
    } while (0)

#define COMPUTE(BUF_)                                                           \
    do {                                                                        \
        bf16x8 bf0 = LOADB(BUF_, 0), bf1 = LOADB(BUF_, 1);                      \
        bf16x8 bf2 = LOADB(BUF_, 2), bf3 = LOADB(BUF_, 3);                      \
        bf16x8 af0 = LOADA(BUF_, 0), af1 = LOADA(BUF_, 1);                      \
        bf16x8 af2 = LOADA(BUF_, 2), af3 = LOADA(BUF_, 3);                      \
        __builtin_amdgcn_s_setprio(1);                                          \
        MFMA16(af0, af1, af2, af3, 0);                                          \
        __builtin_amdgcn_s_setprio(0);                                          \
        bf16x8 ag0 = LOADA(BUF_, 4), ag1 = LOADA(BUF_, 5);                      \
        bf16x8 ag2 = LOADA(BUF_, 6), ag3 = LOADA(BUF_, 7);                      \
        __builtin_amdgcn_s_setprio(1);                                          \
        MFMA16(ag0, ag1, ag2, ag3, 4);                                          \
        __builtin_amdgcn_s_setprio(0);                                          \
    } while (0)

#define TILE(BUF_, VMSTR_, STAGE_STMT)                                          \
    do {                                                                        \
        asm volatile("s_waitcnt vmcnt(" VMSTR_ ")" ::: "memory");               \
        __builtin_amdgcn_sched_barrier(0);                                      \
        __builtin_amdgcn_s_barrier();                                           \
        __builtin_amdgcn_sched_barrier(0);                                      \
        STAGE_STMT;                                                             \
        COMPUTE(BUF_);                                                          \
    } while (0)

    // prologue: 3 tiles in flight
    STAGE(0, 0);
    STAGE(1, 1);
    STAGE(2, 2);

    for (int t = 0; t < NT - 4; t += 4) {
        TILE(0, "8", STAGE(3, t + 3));
        TILE(1, "8", STAGE(0, t + 4));
        TILE(2, "8", STAGE(1, t + 5));
        TILE(3, "8", STAGE(2, t + 6));
    }
    // tail: tiles NT-4..NT-1 (stage last tile, then drain)
    TILE(0, "8", STAGE(3, NT - 1));
    TILE(1, "8", (void)0);
    TILE(2, "4", (void)0);
    TILE(3, "0", (void)0);

#undef TILE
#undef COMPUTE
#undef MFMA16
#undef LOADB
#undef LOADA
#undef STAGE

    // epilogue: frag layout col=lane&15, row=(lane>>4)*4+r
    const int cr0 = brow + wm * 128;
    const int cc0 = bcol + wn * 64;
#pragma unroll
    for (int ni = 0; ni < 4; ++ni) {
        const int col = cc0 + ni * 16 + (lane & 15);
        const float bv = Bi[col];
#pragma unroll
        for (int mi = 0; mi < 8; ++mi) {
#pragma unroll
            for (int r = 0; r < 4; ++r) {
                const int row = cr0 + mi * 16 + (lane >> 4) * 4 + r;
                Out[(size_t)row * N + col] = acc[mi][ni][r] + bv;
            }
        }
    }
}

// ---------------- fallback: fused kernel (ws too small / odd shapes) ----------------
__global__ __launch_bounds__(256, 3)
void awq_gemm_fused(const float* __restrict__ X,
                    const int* __restrict__ QW,
                    const int* __restrict__ QZ,
                    const float* __restrict__ S,
                    const float* __restrict__ Bi,
                    float* __restrict__ Out,
                    int M, int N, int K) {
    const int PQ = K >> 3, NG = K >> 7, ZS = (NG + 7) >> 3;

    __shared__ __align__(16) __bf16 As[BM * BK];
    __shared__ __align__(16) __bf16 Bs[BN * BK];

    const int tid  = threadIdx.x;
    const int lane = tid & 63;
    const int wid  = tid >> 6;

    const int nwg = gridDim.x;
    int bid = blockIdx.x;
    if ((nwg & 7) == 0) {
        const int cpx = nwg >> 3;
        bid = (bid & 7) * cpx + (bid >> 3);
    }
    const int nbn  = N / BN;
    const int brow = (bid / nbn) * BM;
    const int bcol = (bid % nbn) * BN;

    const int wm = wid >> 1;
    const int wn = wid & 1;

    f32x4 acc[4][4];
#pragma unroll
    for (int i = 0; i < 4; ++i)
#pragma unroll
        for (int j = 0; j < 4; ++j)
            acc[i][j] = {0.f, 0.f, 0.f, 0.f};

    int arow[4], acch[4];
#pragma unroll
    for (int it = 0; it < 4; ++it) {
        const int idx = it * 256 + tid;
        arow[it] = idx >> 3;
        acch[it] = idx & 7;
    }

    const int rb    = tid >> 1;
    const int bhalf = tid & 1;
    const int og    = bcol + rb;
    const int* qwrow = QW + (size_t)og * PQ;
    const int* qzrow = QZ + (size_t)og * ZS;
    const float* srow = S + (size_t)og * NG;

    for (int kk = 0; kk < K; kk += BK) {
        bf16x8 areg[4];
#pragma unroll
        for (int it = 0; it < 4; ++it) {
            const float* gx = X + (size_t)(brow + arow[it]) * K + kk + acch[it] * 8;
            const float4 x0 = *(const float4*)gx;
            const float4 x1 = *(const float4*)(gx + 4);
            areg[it][0] = (__bf16)x0.x; areg[it][1] = (__bf16)x0.y;
            areg[it][2] = (__bf16)x0.z; areg[it][3] = (__bf16)x0.w;
            areg[it][4] = (__bf16)x1.x; areg[it][5] = (__bf16)x1.y;
            areg[it][6] = (__bf16)x1.z; areg[it][7] = (__bf16)x1.w;
        }

        const int4 qv = *(const int4*)(qwrow + (kk >> 3) + bhalf * 4);
        const int g  = kk >> 7;
        const int zq = (qzrow[g >> 3] >> ((g & 7) * 4)) & 15;
        const float sf = srow[g];
        const float zs = (float)zq * sf;
        const int vs[4] = {qv.x, qv.y, qv.z, qv.w};
        bf16x8 wregs[4];
#pragma unroll
        for (int w = 0; w < 4; ++w) {
            const int v = vs[w];
#pragma unroll
            for (int j = 0; j < 8; ++j) {
                const float q = (float)((v >> (4 * j)) & 15);
                wregs[w][j] = (__bf16)(q * sf - zs);
            }
        }

#pragma unroll
        for (int it = 0; it < 4; ++it) {
            const int cs = acch[it] ^ (arow[it] & 7);
            *((bf16x8*)(As + (size_t)arow[it] * BK + cs * 8)) = areg[it];
        }
#pragma unroll
        for (int w = 0; w < 4; ++w) {
            const int cs = (bhalf * 4 + w) ^ (rb & 7);
            *((bf16x8*)(Bs + (size_t)rb * BK + cs * 8)) = wregs[w];
        }

        __syncthreads();

#pragma unroll
        for (int ks = 0; ks < 2; ++ks) {
            bf16x8 af[4], bfr[4];
#pragma unroll
            for (int mi = 0; mi < 4; ++mi) {
                const int row = wm * 64 + mi * 16 + (lane & 15);
                const int cs  = (ks * 4 + (lane >> 4)) ^ (row & 7);
                af[mi] = *((const bf16x8*)(As + (size_t)row * BK + cs * 8));
            }
#pragma unroll
            for (int ni = 0; ni < 4; ++ni) {
                const int row = wn * 64 + ni * 16 + (lane & 15);
                const int cs  = (ks * 4 + (lane >> 4)) ^ (row & 7);
                bfr[ni] = *((const bf16x8*)(Bs + (size_t)row * BK + cs * 8));
            }
#pragma unroll
            for (int mi = 0; mi < 4; ++mi)
#pragma unroll
                for (int ni = 0; ni < 4; ++ni)
                    acc[mi][ni] = __builtin_amdgcn_mfma_f32_16x16x32_bf16(
                        af[mi], bfr[ni], acc[mi][ni], 0, 0, 0);
        }
        __syncthreads();
    }

    const int cr0 = brow + wm * 64;
    const int cc0 = bcol + wn * 64;
#pragma unroll
    for (int ni = 0; ni < 4; ++ni) {
        const int col = cc0 + ni * 16 + (lane & 15);
        const float bv = Bi[col];
#pragma unroll
        for (int mi = 0; mi < 4; ++mi) {
#pragma unroll
            for (int r = 0; r < 4; ++r) {
                const int row = cr0 + mi * 16 + (lane >> 4) * 4 + r;
                Out[(size_t)row * N + col] = acc[mi][ni][r] + bv;
            }
        }
    }
}

extern "C" void kernel_launch(void* const* d_in, const int* in_sizes, int n_in,
                              void* d_out, int out_size, void* d_ws, size_t ws_size,
                              hipStream_t stream) {
    const float* X  = (const float*)d_in[0];
    const int*   QW = (const int*)d_in[1];
    const int*   QZ = (const int*)d_in[2];
    const float* S  = (const float*)d_in[3];
    const float* Bi = (const float*)d_in[4];
    float*       Out = (float*)d_out;

    const int O = in_sizes[4];           // 11008
    const int K = in_sizes[1] / O * 8;   // 4096
    const int M = in_sizes[0] / K;       // 8192

    const size_t szX = (size_t)M * K * sizeof(__bf16);   // 64 MiB
    const size_t szW = (size_t)O * K * sizeof(__bf16);   // 86 MiB

    const bool shapes_ok = (M % GBM == 0) && (O % GBN == 0) &&
                           (K % (GBK * 4) == 0) && (K / GBK >= 8);

    if (ws_size >= szX + szW && shapes_ok) {
        __bf16* Xb = (__bf16*)d_ws;
        __bf16* Wb = (__bf16*)((char*)d_ws + szX);
        const size_t n8 = (size_t)M * K / 8;
        cvt_x<<<2048, 256, 0, stream>>>(X, Xb, n8);
        dequant_w<<<O, K / 32, 0, stream>>>(QW, QZ, S, Wb, O, K);
        const int grid = (M / GBM) * (O / GBN);   // 32*43 = 1376
        gemm_pipe<<<grid, 512, 0, stream>>>(Xb, Wb, Bi, Out, M, O, K);
    } else {
        const int grid = (M / BM) * (O / BN);
        awq_gemm_fused<<<grid, 256, 0, stream>>>(X, QW, QZ, S, Bi, Out, M, O, K);
    }
}